// Round 1
// baseline (1300.401 us; speedup 1.0000x reference)
//
#include <hip/hip_runtime.h>

// Problem constants (match reference): x[B][C][H][W], weight[C][1][H][1], bias[C]
#define NB 32
#define NC 384
#define NH 56
#define NW 56

// out[b,c,h,w] = sum_k weight[c,k] * x[b,c,(h+k)%H,w] + bias[c]
// One thread per (b,c,w) column. x column + weights held in registers,
// 56x56 FMA nest fully unrolled (compile-time register indices).
__global__ __launch_bounds__(256) void gcc_Conv2d_64347200028713_kernel(
    const float* __restrict__ x,
    const float* __restrict__ wgt,
    const float* __restrict__ bias,
    float* __restrict__ out)
{
    const int n = blockIdx.x * 256 + threadIdx.x;   // global column id
    const int w = n % NW;                           // column within plane
    const int t = n / NW;                           // plane id = b*NC + c
    const int c = t % NC;

    const float* xcol = x   + (size_t)t * (NH * NW) + w;
    float*       ocol = out + (size_t)t * (NH * NW) + w;

    // Load H-column into registers (reused 56x each).
    float xv[NH];
#pragma unroll
    for (int j = 0; j < NH; ++j) xv[j] = xcol[j * NW];

    // Load per-channel weights into registers (broadcast within wave mostly).
    const float* wrow = wgt + c * NH;
    float wt[NH];
#pragma unroll
    for (int k = 0; k < NH; ++k) wt[k] = wrow[k];

    const float bc = bias[c];

#pragma unroll
    for (int h = 0; h < NH; ++h) {
        float a0 = 0.f, a1 = 0.f, a2 = 0.f, a3 = 0.f;
#pragma unroll
        for (int k = 0; k < NH; k += 4) {
            a0 += wt[k + 0] * xv[(h + k + 0) % NH];
            a1 += wt[k + 1] * xv[(h + k + 1) % NH];
            a2 += wt[k + 2] * xv[(h + k + 2) % NH];
            a3 += wt[k + 3] * xv[(h + k + 3) % NH];
        }
        ocol[h * NW] = ((a0 + a1) + (a2 + a3)) + bc;
    }
}

extern "C" void kernel_launch(void* const* d_in, const int* in_sizes, int n_in,
                              void* d_out, int out_size, void* d_ws, size_t ws_size,
                              hipStream_t stream)
{
    const float* x    = (const float*)d_in[0];
    const float* wgt  = (const float*)d_in[1];
    const float* bias = (const float*)d_in[2];
    float* out        = (float*)d_out;

    const int total_cols = NB * NC * NW;            // 688128
    const int block = 256;
    const int grid = total_cols / block;            // 2688 exactly

    gcc_Conv2d_64347200028713_kernel<<<grid, block, 0, stream>>>(x, wgt, bias, out);
}